// Round 12
// baseline (257.751 us; speedup 1.0000x reference)
//
#include <hip/hip_runtime.h>
#include <math.h>

// BVP Helmholtz-residual PINN via MFMA, round 18.
// Round-16/17 post-mortem: WRITE_SIZE ~141-155MB = accumulator spill. At
// launch_bounds(256,4) the UNIFIED budget is 128/wave, split 64arch+64agpr,
// but acc[4][5]=80 AGPR -> 16 regs spilled x 2.1M threads = 134MB == counter.
// Arch-side diets can't fix an AGPR-side overflow. acc/wave is forced by
// (256 rows x 80 cols)/threads: 80 at 256thr, 40 at 512thr.
// Round-18: pull the TLP lever (only lever with positive measured slope;
// r16 netted +5us DESPITE the spill tax) where acc is small:
// 512 thr, acc[2][5]=40 AGPR, launch_bounds(512,6) -> 3 blocks/CU =
// 24 waves/CU = 6 waves/SIMD. Budget 84 = 40 agpr + <=44 arch. Arch diet:
// L1 writes stream-pairs straight to LDS via ds_write_b32 (kills the
// 40-reg hv block; same bytes at same addresses), A loaded per-kc direct
// (no dbuf; 6-wave TLP covers latency), tanh-rcp kept. LDS 3x43008=129KB.
// Layouts = r13 verbatim (2 rt/wave, jet2 kt=w), all previously verified.

typedef __attribute__((ext_vector_type(8))) short short8;
typedef __attribute__((ext_vector_type(4))) float floatx4;
typedef unsigned short ushort_t;
typedef unsigned int uint_t;

#define PBLK 16
#define NS 5   // jet streams: 0=v 1=dx 2=dy 3=dz 4=weighted-Laplacian

#define CXX 0.09f     // (YC*ZC)^2 = (0.5*0.6)^2
#define CYY 0.1764f   // (XC*ZC)^2 = (0.7*0.6)^2
#define CZZ 0.1225f   // (XC*YC)^2 = (0.7*0.5)^2

__device__ __forceinline__ ushort_t f2bf(float f) {
    uint_t u = __float_as_uint(f);
    return (ushort_t)((u + 0x7FFFu + ((u >> 16) & 1u)) >> 16);  // RNE
}
// pack2bf(f0,f1): {bf16(f0), bf16(f1)} in one u32 (f0 low). Round-half-up.
__device__ __forceinline__ uint_t pack2bf(float f0, float f1) {
    uint_t u0 = __float_as_uint(f0) + 0x8000u;
    uint_t u1 = __float_as_uint(f1) + 0x8000u;
    return __builtin_amdgcn_perm(u1, u0, 0x07060302u);
}
// tanh = (e-1)/(e+1), e = exp(2u); native rcp (no precise-div sequence).
// |u| bounded ~13 by network structure -> e finite, no inf*0 path.
__device__ __forceinline__ float fast_tanh(float u) {
    float e = __expf(2.f * u);
    return (e - 1.f) * __builtin_amdgcn_rcpf(e + 1.f);
}

// ws: 2 layers x 16 row-tiles x 8 kc x 64 lanes x 16B = 256 KB.
// A-frag lane (m=lane&15, qa=lane>>4) slot j:
//   layer0 (W2, natural):  col = kc*32 + 8*qa + j
//   layer1 (W3, permuted): col = kc*32 + 16*(j>>2) + 4*qa + (j&3)
__global__ void prep_split(const float* __restrict__ W2, const float* __restrict__ W3,
                           short8* __restrict__ ws) {
    int t16 = blockIdx.x * blockDim.x + threadIdx.x;  // 0..16383
    int lane = t16 & 63;
    int kc = (t16 >> 6) & 7;
    int tt = (t16 >> 9) & 15;
    int l = t16 >> 13;
    const float* W = l ? W3 : W2;
    int row = tt * 16 + (lane & 15);
    int qa = lane >> 4;
    const float* src = W + row * 256 + kc * 32 + (l ? 4 * qa : 8 * qa);
    float4 va = *(const float4*)src;
    float4 vb = *(const float4*)(src + (l ? 16 : 4));
    float v[8] = {va.x, va.y, va.z, va.w, vb.x, vb.y, vb.z, vb.w};
    short8 hi8;
    #pragma unroll
    for (int j = 0; j < 8; ++j) hi8[j] = (short)f2bf(v[j]);   // RNE (runs once)
    ws[l * 8192 + tt * 512 + kc * 64 + lane] = hi8;
}

__global__ __launch_bounds__(512, 6)
void bvp_main(const float* __restrict__ gx, const float* __restrict__ gy,
              const float* __restrict__ gz, const float* __restrict__ gf,
              const float* __restrict__ W1, const float* __restrict__ b1,
              const float* __restrict__ b2, const float* __restrict__ b3,
              const float* __restrict__ W4, const float* __restrict__ b4,
              const short8* __restrict__ wsA, float* __restrict__ out, int N) {
    __shared__ short8 Bsh[NS * 8 * 64];  // 40960 B: B[s][kt][lane]
    __shared__ float red[8][16][4];      // 2 KB cross-wave reduction scratch

    const int tid = threadIdx.x;
    const int w = tid >> 6, lane = tid & 63;   // w in 0..7
    const int n15 = lane & 15, qc = lane >> 4;
    const int pbase = blockIdx.x * PBLK;
    const short8* __restrict__ wsA3 = wsA + 8192;

    floatx4 acc[2][NS];  // 2 row-tiles (32 rows) x 5 streams = 40 AGPR

    // ---------------- layer 1 (VALU) -> B fragments ----------------
    // Pair-streamed: compute k-slots (2rp, 2rp+1), pack, ds_write_b32
    // straight to LDS -> no 40-reg hv block (arch diet for 6 waves/SIMD).
    // Bytes land exactly where the old b128 u4[rp] did.
    {
        const int pp = tid & 15, u8 = tid >> 4;     // u8 0..31: neurons 8*u8..+7
        const int kt = u8 >> 2, qb = u8 & 3;        // k-slot qb*8+r
        const int pidx = min(pbase + pp, N - 1);
        const float xi = gx[pidx], yi = gy[pidx], zi = gz[pidx], fi = gf[pidx];
        uint_t* const Bw = (uint_t*)Bsh;
        const int base4 = ((kt * 64) + qb * 16 + pp) * 4;   // s=0 u32 index
        #pragma unroll
        for (int rp = 0; rp < 4; ++rp) {
            const int i0 = u8 * 8 + 2 * rp;
            float4 wa = *(const float4*)(W1 + 4 * i0);
            float4 wb = *(const float4*)(W1 + 4 * i0 + 4);
            float u0 = fmaf(wa.x, xi, fmaf(wa.y, yi, fmaf(wa.z, zi, fmaf(wa.w, fi, b1[i0]))));
            float u1 = fmaf(wb.x, xi, fmaf(wb.y, yi, fmaf(wb.z, zi, fmaf(wb.w, fi, b1[i0 + 1]))));
            float t0 = fast_tanh(u0), s0 = 1.f - t0 * t0, c0 = -2.f * t0 * s0;
            float t1 = fast_tanh(u1), s1 = 1.f - t1 * t1, c1 = -2.f * t1 * s1;
            float wq0 = fmaf(CXX * wa.x, wa.x, fmaf(CYY * wa.y, wa.y, CZZ * wa.z * wa.z));
            float wq1 = fmaf(CXX * wb.x, wb.x, fmaf(CYY * wb.y, wb.y, CZZ * wb.z * wb.z));
            Bw[base4 + 0 * 2048 + rp] = pack2bf(t0, t1);
            Bw[base4 + 1 * 2048 + rp] = pack2bf(s0 * wa.x, s1 * wb.x);
            Bw[base4 + 2 * 2048 + rp] = pack2bf(s0 * wa.y, s1 * wb.y);
            Bw[base4 + 3 * 2048 + rp] = pack2bf(s0 * wa.z, s1 * wb.z);
            Bw[base4 + 4 * 2048 + rp] = pack2bf(c0 * wq0, c1 * wq1);
        }
    }
    __syncthreads();

    // K-loop: direct A (L2-resident) and B (LDS) loads; minimal live set.
    auto run_gemm = [&](const short8* __restrict__ A) {
        #pragma unroll
        for (int rt = 0; rt < 2; ++rt)
            #pragma unroll
            for (int ct = 0; ct < NS; ++ct) acc[rt][ct] = (floatx4){0.f, 0.f, 0.f, 0.f};
        #pragma unroll
        for (int kc = 0; kc < 8; ++kc) {
            short8 av[2];
            #pragma unroll
            for (int rt = 0; rt < 2; ++rt)
                av[rt] = A[(2 * w + rt) * 512 + kc * 64 + lane];
            #pragma unroll
            for (int ct = 0; ct < NS; ++ct) {
                const short8 b = Bsh[(ct * 8 + kc) * 64 + lane];
                #pragma unroll
                for (int rt = 0; rt < 2; ++rt)
                    acc[rt][ct] = __builtin_amdgcn_mfma_f32_16x16x32_bf16(av[rt], b, acc[rt][ct], 0, 0, 0);
            }
        }
    };

    // ---------------- GEMM 2 ----------------
    run_gemm(wsA);
    __syncthreads();   // all waves done reading layer-2 B

    // ---------------- jet 2 (lane-local) -> new B fragments ----------------
    // Wave w's 32 rows are exactly k-tile w; permuted k-order
    // k(qc,j)=16(j>>2)+4qc+(j&3) makes the repack lane-local.
    // L-stream: L_h = s*L_u + c*(cxx*ux^2 + cyy*uy^2 + czz*uz^2).
    #pragma unroll
    for (int rt = 0; rt < 2; ++rt) {
        const float4 bb = *(const float4*)(b2 + w * 32 + rt * 16 + qc * 4);
        const float bbv[4] = {bb.x, bb.y, bb.z, bb.w};
        #pragma unroll
        for (int r = 0; r < 4; ++r) {
            float t = fast_tanh(acc[rt][0][r] + bbv[r]);
            float s = 1.f - t * t, c = -2.f * t * s;
            float ux = acc[rt][1][r], uy = acc[rt][2][r], uz = acc[rt][3][r];
            float wq = fmaf(CXX * ux, ux, fmaf(CYY * uy, uy, CZZ * uz * uz));
            acc[rt][0][r] = t;
            acc[rt][1][r] = s * ux; acc[rt][2][r] = s * uy; acc[rt][3][r] = s * uz;
            acc[rt][4][r] = fmaf(s, acc[rt][4][r], c * wq);
        }
    }
    #pragma unroll
    for (int s = 0; s < NS; ++s) {
        union { short8 s8; uint_t u4[4]; } v;
        v.u4[0] = pack2bf(acc[0][s][0], acc[0][s][1]);
        v.u4[1] = pack2bf(acc[0][s][2], acc[0][s][3]);
        v.u4[2] = pack2bf(acc[1][s][0], acc[1][s][1]);
        v.u4[3] = pack2bf(acc[1][s][2], acc[1][s][3]);
        Bsh[(s * 8 + w) * 64 + lane] = v.s8;   // kt = w, own lane slot
    }
    __syncthreads();

    // ---------------- GEMM 3 ----------------
    run_gemm(wsA3);

    // ---------------- jet 3 + layer-4 partials (lane-local) ----------------
    // Layer-4 is linear: needs only value and L streams.
    float pt[4] = {0.f, 0.f, 0.f, 0.f};
    #pragma unroll
    for (int rt = 0; rt < 2; ++rt) {
        const int rb = w * 32 + rt * 16 + qc * 4;
        const float4 bb = *(const float4*)(b3 + rb);
        const float4 w0 = *(const float4*)(W4 + rb);
        const float4 w1 = *(const float4*)(W4 + 256 + rb);
        const float bbv[4] = {bb.x, bb.y, bb.z, bb.w};
        const float w0v[4] = {w0.x, w0.y, w0.z, w0.w};
        const float w1v[4] = {w1.x, w1.y, w1.z, w1.w};
        #pragma unroll
        for (int r = 0; r < 4; ++r) {
            float t = fast_tanh(acc[rt][0][r] + bbv[r]);
            float s = 1.f - t * t, c = -2.f * t * s;
            float ux = acc[rt][1][r], uy = acc[rt][2][r], uz = acc[rt][3][r];
            float wq = fmaf(CXX * ux, ux, fmaf(CYY * uy, uy, CZZ * uz * uz));
            float hL = fmaf(s, acc[rt][4][r], c * wq);
            pt[0] = fmaf(w0v[r], t, pt[0]);
            pt[1] = fmaf(w0v[r], hL, pt[1]);
            pt[2] = fmaf(w1v[r], t, pt[2]);
            pt[3] = fmaf(w1v[r], hL, pt[3]);
        }
    }
    #pragma unroll
    for (int k = 0; k < 4; ++k) {
        pt[k] += __shfl_xor(pt[k], 16, 64);
        pt[k] += __shfl_xor(pt[k], 32, 64);
    }
    if (qc == 0)
        *(float4*)&red[w][n15][0] = make_float4(pt[0], pt[1], pt[2], pt[3]);
    __syncthreads();

    if (tid < 16 && (pbase + tid) < N) {
        const int n = pbase + tid;
        float s4[4] = {0.f, 0.f, 0.f, 0.f};
        #pragma unroll
        for (int ww = 0; ww < 8; ++ww)
            #pragma unroll
            for (int k = 0; k < 4; ++k) s4[k] += red[ww][tid][k];
        const float fi = gf[n];
        const float PI = 3.14159265358979323846f;
        const float kw = 2.f * PI * (fi * 500.f + 100.f) / 343.f;
        const float vol = 0.7f * 0.5f * 0.6f;
        const float kk = vol * vol * kw * kw;
        const float pr = s4[0] + b4[0];
        const float pim = s4[2] + b4[1];
        out[n]     = 2.0f * s4[1] + kk * (pr * 2.0f + 0.1f);
        out[N + n] = 1.5f * s4[3] + kk * (pim * 1.5f - 0.05f);
    }
}

extern "C" void kernel_launch(void* const* d_in, const int* in_sizes, int n_in,
                              void* d_out, int out_size, void* d_ws, size_t ws_size,
                              hipStream_t stream) {
    const float* x = (const float*)d_in[0];
    const float* y = (const float*)d_in[1];
    const float* z = (const float*)d_in[2];
    const float* f = (const float*)d_in[3];
    const float* W1 = (const float*)d_in[4];
    const float* b1 = (const float*)d_in[5];
    const float* W2 = (const float*)d_in[6];
    const float* b2 = (const float*)d_in[7];
    const float* W3 = (const float*)d_in[8];
    const float* b3 = (const float*)d_in[9];
    const float* W4 = (const float*)d_in[10];
    const float* b4 = (const float*)d_in[11];
    float* out = (float*)d_out;
    const int N = in_sizes[0];
    const int grid = (N + PBLK - 1) / PBLK;

    prep_split<<<64, 256, 0, stream>>>(W2, W3, (short8*)d_ws);
    bvp_main<<<grid, 512, 0, stream>>>(x, y, z, f, W1, b1, b2, b3, W4, b4,
                                       (const short8*)d_ws, out, N);
}